// Round 7
// baseline (2279.792 us; speedup 1.0000x reference)
//
#include <hip/hip_runtime.h>

typedef __bf16 bf16;
typedef __bf16 bf16x8 __attribute__((ext_vector_type(8)));
typedef float floatx4 __attribute__((ext_vector_type(4)));

#define BATCH 128
#define SEQ   2048
#define HID   128
#define TWOH  256
#define CH    128
#define NCH   16
#define MTOT  (BATCH * SEQ)   // 262144
#define NBLK  (MTOT / CH)     // 2048

__device__ __forceinline__ float fast_tanh(float x) {
    float e = __builtin_amdgcn_exp2f(2.88539008177793f * x);
    return 1.0f - 2.0f * __builtin_amdgcn_rcpf(e + 1.0f);
}
__device__ __forceinline__ float fast_sigmoid(float x) {
    return __builtin_amdgcn_rcpf(1.0f + __builtin_amdgcn_exp2f(-1.44269504088896f * x));
}

union PK4 { unsigned long long u; bf16 h[4]; };
union PK2 { unsigned int u; bf16 h[2]; };

// ---- one-time f32 -> bf16 conversion of Wx2h (both layers) ----
__global__ __launch_bounds__(256) void convert_w_k(const float* __restrict__ W,
                                                   bf16* __restrict__ Wb) {
    int i = blockIdx.x * 256 + threadIdx.x;   // 16384 float4 groups
    float4 v = ((const float4*)W)[i];
    PK4 pk;
    pk.h[0] = (bf16)v.x; pk.h[1] = (bf16)v.y;
    pk.h[2] = (bf16)v.z; pk.h[3] = (bf16)v.w;
    ((unsigned long long*)Wb)[i] = pk.u;
}

// ===========================================================================
// Mega-kernel: one block per (b,chunk) = 128 t-rows. Both layers fused.
// Per layer: GEMM (4 stages of 64 W-rows, Bs=16KB), tanh packed bf16 in regs,
// publish per-chunk column sums (release flag), decoupled lookback over
// predecessor chunks (acquire spin), then emit: layer0 -> h0 into As (LDS),
// layer1 -> fc dot + sigmoids + masked loss.
// 512 thr = 8 waves: wr=wid>>1 (32-row stripe), wc=wid&1 (32-col substripe).
// D tile mapping (R5-validated): row = wr*32+mi*16+quad*4+rr,
// col = s*64+wc*32+ni*16+l16. Row scan: rr -> quad(shfl) -> mi -> wr(cst LDS).
// ===========================================================================
__global__ __launch_bounds__(512, 4) void mega_k(
    const float* __restrict__ x, const bf16* __restrict__ Wb,
    float* __restrict__ Ppart, int* __restrict__ flags,
    const float* __restrict__ Wfc, const int* __restrict__ xlen,
    const float* __restrict__ xlab, float* __restrict__ out)
{
    __shared__ bf16 As[128 * 128];       // 32 KB: x tile, later h0 tile
    __shared__ bf16 Bs[64 * 128];        // 16 KB: W stage
    __shared__ float cst[4][256];        // per-stripe column sums
    __shared__ float po[256];            // lookback offsets
    __shared__ float zbuf[2][128][2];
    __shared__ float red[2];

    const int tid  = threadIdx.x;
    const int lane = tid & 63;
    const int wid  = tid >> 6;
    const int wr   = wid >> 1;
    const int wc   = wid & 1;
    const int quad = lane >> 4;
    const int l16  = lane & 15;
    const int blk  = blockIdx.x;
    const int c    = blk & (NCH - 1);

    // ---- stage x tile -> As (bf16, XOR-swizzled by row&7) ----
    {
        const float4* A4 = (const float4*)(x + (long)blk * CH * HID);
        #pragma unroll
        for (int it = 0; it < 8; ++it) {
            int i  = it * 512 + tid;
            int r  = i >> 5;
            int c4 = i & 31;
            float4 v = A4[i];
            int g = c4 >> 1, hf = c4 & 1;
            PK4 pk;
            pk.h[0] = (bf16)v.x; pk.h[1] = (bf16)v.y;
            pk.h[2] = (bf16)v.z; pk.h[3] = (bf16)v.w;
            *(unsigned long long*)&As[r * 128 + ((g ^ (r & 7)) << 3) + (hf << 2)] = pk.u;
        }
    }

    unsigned int gpk[4][8];   // rounded tanh values, 2 per reg

    #pragma unroll
    for (int layer = 0; layer < 2; ++layer) {
        const bf16* Wl = Wb + layer * TWOH * HID;
        float* Pp = Ppart + (long)layer * NBLK * 256;
        int* fl = flags + layer * NBLK;

        // ---- GEMM: 4 stages of 64 output cols ----
        #pragma unroll
        for (int s = 0; s < 4; ++s) {
            __syncthreads();   // As ready / prior Bs+cst reads done
            {
                // Bs = 64 rows x 128 cols = 1024 uint4: row = i>>4, group = i&15
                const uint4* W8 = (const uint4*)(Wl + s * 64 * HID);
                #pragma unroll
                for (int it = 0; it < 2; ++it) {
                    int i = it * 512 + tid;
                    int r = i >> 4;
                    int g = i & 15;
                    uint4 v = W8[i];
                    *(uint4*)&Bs[r * 128 + ((g ^ (r & 7)) << 3)] = v;
                }
            }
            __syncthreads();

            floatx4 acc[2][2];
            #pragma unroll
            for (int a = 0; a < 2; ++a)
                #pragma unroll
                for (int b2 = 0; b2 < 2; ++b2) acc[a][b2] = (floatx4){0.f, 0.f, 0.f, 0.f};

            #pragma unroll
            for (int kk = 0; kk < 128; kk += 32) {
                bf16x8 af[2], bfr[2];
                int kg = (kk >> 3) + quad;
                #pragma unroll
                for (int mi = 0; mi < 2; ++mi) {
                    int r = wr * 32 + mi * 16 + l16;
                    af[mi] = *(const bf16x8*)&As[r * 128 + ((kg ^ (r & 7)) << 3)];
                }
                #pragma unroll
                for (int ni = 0; ni < 2; ++ni) {
                    int n = wc * 32 + ni * 16 + l16;
                    bfr[ni] = *(const bf16x8*)&Bs[n * 128 + ((kg ^ (n & 7)) << 3)];
                }
                #pragma unroll
                for (int mi = 0; mi < 2; ++mi)
                    #pragma unroll
                    for (int ni = 0; ni < 2; ++ni)
                        acc[mi][ni] = __builtin_amdgcn_mfma_f32_16x16x32_bf16(
                            af[mi], bfr[ni], acc[mi][ni], 0, 0, 0);
            }

            // tanh -> bf16 pack (rounded) + column sums of rounded values
            #pragma unroll
            for (int ni = 0; ni < 2; ++ni) {
                float cs = 0.f;
                #pragma unroll
                for (int mi = 0; mi < 2; ++mi)
                    #pragma unroll
                    for (int rp = 0; rp < 2; ++rp) {
                        PK2 pk;
                        pk.h[0] = (bf16)fast_tanh(acc[mi][ni][rp * 2]);
                        pk.h[1] = (bf16)fast_tanh(acc[mi][ni][rp * 2 + 1]);
                        gpk[s][mi * 4 + ni * 2 + rp] = pk.u;
                        cs += (float)pk.h[0] + (float)pk.h[1];
                    }
                cs += __shfl_xor(cs, 16);
                cs += __shfl_xor(cs, 32);
                if (quad == 0)
                    cst[wr][s * 64 + wc * 32 + ni * 16 + l16] = cs;
            }
        }
        __syncthreads();

        // ---- publish chunk totals + flag (release) ----
        if (tid < 256)
            Pp[(long)blk * 256 + tid] = cst[0][tid] + cst[1][tid] + cst[2][tid] + cst[3][tid];
        __threadfence();
        __syncthreads();
        if (tid == 0)
            __hip_atomic_store(&fl[blk], 1, __ATOMIC_RELEASE, __HIP_MEMORY_SCOPE_AGENT);

        // ---- decoupled lookback over predecessor chunks ----
        if (tid < 256) {
            float off = 0.f;
            for (int p = blk - c; p < blk; ++p) {
                while (__hip_atomic_load(&fl[p], __ATOMIC_ACQUIRE,
                                         __HIP_MEMORY_SCOPE_AGENT) == 0)
                    __builtin_amdgcn_s_sleep(1);
                off += Pp[(long)p * 256 + tid];
            }
            po[tid] = off;
        }
        __syncthreads();

        // ---- emission ----
        if (layer == 0) {
            // h0 = P2 - relu(P1)*g2 -> As (bf16, swizzled), overwriting x tile
            #pragma unroll
            for (int sp = 0; sp < 2; ++sp)
                #pragma unroll
                for (int ni = 0; ni < 2; ++ni) {
                    int col = sp * 64 + wc * 32 + ni * 16 + l16;   // [0,128)
                    float p1v[2][4], pr2[2][4], g2v[2][4];
                    #pragma unroll
                    for (int gate = 0; gate < 2; ++gate) {
                        float mibase = 0.f;
                        #pragma unroll
                        for (int mi = 0; mi < 2; ++mi) {
                            PK2 a0, a1;
                            a0.u = gpk[sp + gate * 2][mi * 4 + ni * 2];
                            a1.u = gpk[sp + gate * 2][mi * 4 + ni * 2 + 1];
                            float g0 = a0.h[0], g1 = a0.h[1], g2 = a1.h[0], g3 = a1.h[1];
                            float s0 = g0, s1 = s0 + g1, s2 = s1 + g2, s3 = s2 + g3;
                            float xq = s3;
                            float t = __shfl_up(xq, 16); if (quad >= 1) xq += t;
                            t = __shfl_up(xq, 32); if (quad >= 2) xq += t;
                            float excl = mibase + xq - s3;
                            if (gate == 0) {
                                p1v[mi][0] = excl + s0; p1v[mi][1] = excl + s1;
                                p1v[mi][2] = excl + s2; p1v[mi][3] = excl + s3;
                            } else {
                                pr2[mi][0] = excl + s0; pr2[mi][1] = excl + s1;
                                pr2[mi][2] = excl + s2; pr2[mi][3] = excl + s3;
                                g2v[mi][0] = g0; g2v[mi][1] = g1;
                                g2v[mi][2] = g2; g2v[mi][3] = g3;
                            }
                            mibase += __shfl(xq, 48 + l16);
                        }
                        int cf = col + gate * 128;
                        float base = po[cf];
                        if (wr > 0) base += cst[0][cf];
                        if (wr > 1) base += cst[1][cf];
                        if (wr > 2) base += cst[2][cf];
                        #pragma unroll
                        for (int mi = 0; mi < 2; ++mi)
                            #pragma unroll
                            for (int rr = 0; rr < 4; ++rr) {
                                if (gate == 0) p1v[mi][rr] += base;
                                else           pr2[mi][rr] += base;
                            }
                    }
                    #pragma unroll
                    for (int mi = 0; mi < 2; ++mi)
                        #pragma unroll
                        for (int rr = 0; rr < 4; ++rr) {
                            int row = wr * 32 + mi * 16 + quad * 4 + rr;
                            float h = pr2[mi][rr] - fmaxf(p1v[mi][rr], 0.f) * g2v[mi][rr];
                            int addr = row * 128 + ((((col >> 3) ^ (row & 7))) << 3) + (col & 7);
                            As[addr] = (bf16)h;
                        }
                }
        } else {
            // layer-1: h1 -> fc dot -> softmax[:,1]=sigmoid(z1-z0) -> sigmoid -> loss
            float z0a[2][4], z1a[2][4];
            #pragma unroll
            for (int mi = 0; mi < 2; ++mi)
                #pragma unroll
                for (int rr = 0; rr < 4; ++rr) { z0a[mi][rr] = 0.f; z1a[mi][rr] = 0.f; }
            #pragma unroll
            for (int sp = 0; sp < 2; ++sp)
                #pragma unroll
                for (int ni = 0; ni < 2; ++ni) {
                    int col = sp * 64 + wc * 32 + ni * 16 + l16;
                    float w0c = Wfc[2 * HID + col];
                    float w1c = Wfc[3 * HID + col];
                    float p1v[2][4], pr2[2][4], g2v[2][4];
                    #pragma unroll
                    for (int gate = 0; gate < 2; ++gate) {
                        float mibase = 0.f;
                        #pragma unroll
                        for (int mi = 0; mi < 2; ++mi) {
                            PK2 a0, a1;
                            a0.u = gpk[sp + gate * 2][mi * 4 + ni * 2];
                            a1.u = gpk[sp + gate * 2][mi * 4 + ni * 2 + 1];
                            float g0 = a0.h[0], g1 = a0.h[1], g2 = a1.h[0], g3 = a1.h[1];
                            float s0 = g0, s1 = s0 + g1, s2 = s1 + g2, s3 = s2 + g3;
                            float xq = s3;
                            float t = __shfl_up(xq, 16); if (quad >= 1) xq += t;
                            t = __shfl_up(xq, 32); if (quad >= 2) xq += t;
                            float excl = mibase + xq - s3;
                            if (gate == 0) {
                                p1v[mi][0] = excl + s0; p1v[mi][1] = excl + s1;
                                p1v[mi][2] = excl + s2; p1v[mi][3] = excl + s3;
                            } else {
                                pr2[mi][0] = excl + s0; pr2[mi][1] = excl + s1;
                                pr2[mi][2] = excl + s2; pr2[mi][3] = excl + s3;
                                g2v[mi][0] = g0; g2v[mi][1] = g1;
                                g2v[mi][2] = g2; g2v[mi][3] = g3;
                            }
                            mibase += __shfl(xq, 48 + l16);
                        }
                        int cf = col + gate * 128;
                        float base = po[cf];
                        if (wr > 0) base += cst[0][cf];
                        if (wr > 1) base += cst[1][cf];
                        if (wr > 2) base += cst[2][cf];
                        #pragma unroll
                        for (int mi = 0; mi < 2; ++mi)
                            #pragma unroll
                            for (int rr = 0; rr < 4; ++rr) {
                                if (gate == 0) p1v[mi][rr] += base;
                                else           pr2[mi][rr] += base;
                            }
                    }
                    #pragma unroll
                    for (int mi = 0; mi < 2; ++mi)
                        #pragma unroll
                        for (int rr = 0; rr < 4; ++rr) {
                            float h = pr2[mi][rr] - fmaxf(p1v[mi][rr], 0.f) * g2v[mi][rr];
                            z0a[mi][rr] += h * w0c;
                            z1a[mi][rr] += h * w1c;
                        }
                }
            #pragma unroll
            for (int mi = 0; mi < 2; ++mi)
                #pragma unroll
                for (int rr = 0; rr < 4; ++rr) {
                    float z0 = z0a[mi][rr], z1 = z1a[mi][rr];
                    z0 += __shfl_xor(z0, 1); z1 += __shfl_xor(z1, 1);
                    z0 += __shfl_xor(z0, 2); z1 += __shfl_xor(z1, 2);
                    z0 += __shfl_xor(z0, 4); z1 += __shfl_xor(z1, 4);
                    z0 += __shfl_xor(z0, 8); z1 += __shfl_xor(z1, 8);
                    if (l16 == 0) {
                        int row = wr * 32 + mi * 16 + quad * 4 + rr;
                        zbuf[wc][row][0] = z0;
                        zbuf[wc][row][1] = z1;
                    }
                }
            __syncthreads();
            float lsum = 0.f;
            if (tid < 128) {
                int row = tid;
                int b = blk >> 4;
                float z0 = zbuf[0][row][0] + zbuf[1][row][0];
                float z1 = zbuf[0][row][1] + zbuf[1][row][1];
                float o1 = fast_sigmoid(z1 - z0);
                float sg = fast_sigmoid(o1);
                float d = xlab[b] - sg;
                if (c * CH + row < xlen[b]) lsum = d * d;
                lsum += __shfl_xor(lsum, 1);
                lsum += __shfl_xor(lsum, 2);
                lsum += __shfl_xor(lsum, 4);
                lsum += __shfl_xor(lsum, 8);
                lsum += __shfl_xor(lsum, 16);
                lsum += __shfl_xor(lsum, 32);
                if (lane == 0) red[wid] = lsum;
            }
            __syncthreads();
            if (tid == 0) atomicAdd(out, red[0] + red[1]);
        }
    }
}

extern "C" void kernel_launch(void* const* d_in, const int* in_sizes, int n_in,
                              void* d_out, int out_size, void* d_ws, size_t ws_size,
                              hipStream_t stream) {
    const float* x    = (const float*)d_in[0];
    const int*   xlen = (const int*)d_in[1];
    const float* xlab = (const float*)d_in[2];
    const float* Wx2h = (const float*)d_in[3];  // [2,256,128] f32
    const float* Wfc  = (const float*)d_in[4];  // [2,2,128] f32
    float* out = (float*)d_out;

    char* ws = (char*)d_ws;
    float* Ppart = (float*)ws;                                  // 2*2048*256*4 = 4 MiB
    int*   flags = (int*)(ws + (size_t)2 * NBLK * 256 * 4);     // 16 KiB
    bf16*  Wb    = (bf16*)(ws + (size_t)2 * NBLK * 256 * 4 + 2 * NBLK * 4);

    hipMemsetAsync(d_out, 0, sizeof(float), stream);
    hipMemsetAsync(flags, 0, (size_t)2 * NBLK * 4, stream);
    convert_w_k<<<64, 256, 0, stream>>>(Wx2h, Wb);

    mega_k<<<NBLK, 512, 0, stream>>>(x, Wb, Ppart, flags, Wfc, xlen, xlab, out);
}